// Round 2
// baseline (173.003 us; speedup 1.0000x reference)
//
#include <hip/hip_runtime.h>
#include <stdint.h>

#define B_ 2
#define S_ 2048
#define E_ 1024
#define H_ 16
#define D_ 64
#define R_ 16

typedef short s16x8 __attribute__((ext_vector_type(8)));
typedef float f32x4 __attribute__((ext_vector_type(4)));

#define K1_ 0.045084220027780106f   // log2(e)/32
#define K0_ -28.853900817779268f    // -20*log2(e)

// fp32 -> bf16 bits, round-to-nearest (ties away)
__device__ __forceinline__ unsigned short f2bf(float f) {
  union { float f; unsigned u; } v; v.f = f;
  return (unsigned short)((v.u + 0x8000u) >> 16);
}

// pack two fp32 -> one dword of 2x bf16 (lo=a, hi=b) — guide T12 verbatim recipe
__device__ __forceinline__ unsigned cvt_pk_bf16(float a, float b) {
  unsigned r;
  asm("v_cvt_pk_bf16_f32 %0, %1, %2" : "=v"(r) : "v"(a), "v"(b));
  return r;
}

// async global->LDS, 16B per lane
__device__ __forceinline__ void load_lds16(const void* g, void* l) {
  __builtin_amdgcn_global_load_lds(
      (__attribute__((address_space(1))) void*)(g),
      (__attribute__((address_space(3))) void*)(l), 16, 0, 0);
}

// ---------------- unified prep kernel ----------------
// blocks [0,4096): x fp32->bf16
// blocks [4096,4608): Wq/Wk transpose -> Wt[(which,h,d),e]  (Wq scaled by K1)
// blocks [4608,8704): fused Wv = Wvd@Wvu -> Wt[(2,h,d),e]
// blocks [8704,8716): biases (bq scaled by K1)
__global__ void k_prep(const float* __restrict__ x,
                       const float* __restrict__ Wq, const float* __restrict__ Wk,
                       const float* __restrict__ Wvd, const float* __restrict__ Wvu,
                       const float* __restrict__ bq, const float* __restrict__ bk,
                       const float* __restrict__ bvd, const float* __restrict__ bvu,
                       unsigned short* __restrict__ xb, unsigned short* __restrict__ Wt,
                       float* __restrict__ ball) {
  __shared__ float T[64][65];
  const int blk = blockIdx.x;
  const int t = threadIdx.x;
  if (blk < 4096) {
    int i = (blk * 256 + t) * 4;
    float4 v = *(const float4*)(x + i);
    ushort4 o;
    o.x = f2bf(v.x); o.y = f2bf(v.y); o.z = f2bf(v.z); o.w = f2bf(v.w);
    *(ushort4*)(xb + i) = o;
  } else if (blk < 4608) {
    const int bb = blk - 4096;
    const int which = bb >> 8;
    const int h = (bb >> 4) & 15;
    const int et = bb & 15;
    const float scl = which ? 1.f : K1_;
    const float* src = (which ? Wk : Wq) + (h * E_ + et * 64) * D_;
#pragma unroll
    for (int pr = 0; pr < 4; ++pr) {
      const int row = pr * 16 + (t >> 4);
      const int col = (t & 15) * 4;
      float4 v = *(const float4*)(src + row * 64 + col);
      T[row][col] = v.x; T[row][col + 1] = v.y; T[row][col + 2] = v.z; T[row][col + 3] = v.w;
    }
    __syncthreads();
#pragma unroll
    for (int pr = 0; pr < 4; ++pr) {
      const int d = pr * 16 + (t >> 4);
      const int ec = (t & 15) * 4;
      ushort4 o;
      o.x = f2bf(T[ec][d] * scl); o.y = f2bf(T[ec + 1][d] * scl);
      o.z = f2bf(T[ec + 2][d] * scl); o.w = f2bf(T[ec + 3][d] * scl);
      *(ushort4*)(Wt + ((which << 10) + h * 64 + d) * 1024 + et * 64 + ec) = o;
    }
  } else if (blk < 8704) {
    const int idx = (blk - 4608) * 256 + t;  // 1M
    const int row = idx >> 10;                // h*64+d
    const int e = idx & 1023;
    const int h = row >> 6, d = row & 63;
    const float4* wd4 = (const float4*)(Wvd + (h << 14) + e * 16);
    const float* wu = Wvu + h * R_ * D_ + d;
    float acc = 0.f;
#pragma unroll
    for (int r4 = 0; r4 < 4; ++r4) {
      float4 a = wd4[r4];
      acc += a.x * wu[(r4 * 4 + 0) * 64];
      acc += a.y * wu[(r4 * 4 + 1) * 64];
      acc += a.z * wu[(r4 * 4 + 2) * 64];
      acc += a.w * wu[(r4 * 4 + 3) * 64];
    }
    Wt[(2048 + row) * 1024 + e] = f2bf(acc);
  } else {
    int n = (blk - 8704) * 256 + t;  // 3072
    int which = n >> 10;
    int hd = n & 1023;
    int h = hd >> 6, d = hd & 63;
    float v;
    if (which == 0) v = bq[hd] * K1_;
    else if (which == 1) v = bk[hd];
    else {
      v = bvu[hd];
#pragma unroll
      for (int r = 0; r < R_; ++r) v += bvd[h * R_ + r] * Wvu[(h * R_ + r) * D_ + d];
    }
    ball[n] = v;
  }
}

// ---------------- fused QKV GEMM (R4-proven structure, untouched) ----------------
// cols [0,1024): Q*K1 -> (bh, s, d); [1024,2048): K -> (bh, s, d);
// [2048,3072): V -> transposed (bh, d, s)

__global__ __launch_bounds__(256, 2) void k_gemm_qkv(
    const unsigned short* __restrict__ X, const unsigned short* __restrict__ Wt,
    const float* __restrict__ ball,
    unsigned short* __restrict__ Qb, unsigned short* __restrict__ Kb,
    unsigned short* __restrict__ Vb) {
  __shared__ unsigned short As[128 * 32];
  __shared__ unsigned short Bs[128 * 32];
  const int tid = threadIdx.x;
  const int lane = tid & 63, wave = tid >> 6;
  const int quad = lane >> 4, l16 = lane & 15;
  const int mBase = blockIdx.y * 128, nBase = blockIdx.x * 128;
  const int wm = (wave & 1) * 64, wn = (wave >> 1) * 64;
  const int lrow = lane >> 2, lcol = (lane & 3) * 8;

  f32x4 acc[4][4];
#pragma unroll
  for (int mi = 0; mi < 4; ++mi)
#pragma unroll
    for (int ni = 0; ni < 4; ++ni) acc[mi][ni] = (f32x4){0.f, 0.f, 0.f, 0.f};

  for (int k0 = 0; k0 < E_; k0 += 32) {
#pragma unroll
    for (int i = 0; i < 2; ++i) {
      const int r0 = __builtin_amdgcn_readfirstlane((wave + i * 4) * 16);
      load_lds16(X + (mBase + r0 + lrow) * E_ + k0 + lcol, &As[r0 * 32]);
      load_lds16(Wt + (nBase + r0 + lrow) * E_ + k0 + lcol, &Bs[r0 * 32]);
    }
    __syncthreads();
    s16x8 af[4], bfr[4];
#pragma unroll
    for (int mi = 0; mi < 4; ++mi)
      af[mi] = *(const s16x8*)&As[(wm + mi * 16 + l16) * 32 + quad * 8];
#pragma unroll
    for (int ni = 0; ni < 4; ++ni)
      bfr[ni] = *(const s16x8*)&Bs[(wn + ni * 16 + l16) * 32 + quad * 8];
#pragma unroll
    for (int mi = 0; mi < 4; ++mi)
#pragma unroll
      for (int ni = 0; ni < 4; ++ni)
        acc[mi][ni] = __builtin_amdgcn_mfma_f32_16x16x32_bf16(af[mi], bfr[ni], acc[mi][ni], 0, 0, 0);
    __syncthreads();
  }

  const int which = nBase >> 10;  // uniform per block
#pragma unroll
  for (int ni = 0; ni < 4; ++ni) {
    const int n = nBase + wn + ni * 16 + l16;
    const int nh = n & 1023;
    const int h = nh >> 6, d = nh & 63;
    const float bias = ball[n];
#pragma unroll
    for (int mi = 0; mi < 4; ++mi) {
      const int m0 = mBase + wm + mi * 16 + quad * 4;
      const int b = m0 >> 11;
      const int s = m0 & 2047;
      const int bh = b * H_ + h;
      if (which == 2) {
        ushort4 pk;
        pk.x = f2bf(acc[mi][ni][0] + bias);
        pk.y = f2bf(acc[mi][ni][1] + bias);
        pk.z = f2bf(acc[mi][ni][2] + bias);
        pk.w = f2bf(acc[mi][ni][3] + bias);
        *(ushort4*)(Vb + (bh * D_ + d) * S_ + s) = pk;  // transposed store
      } else {
        unsigned short* dst = (which == 0 ? Qb : Kb) + (bh * S_ + s) * D_ + d;
#pragma unroll
        for (int r = 0; r < 4; ++r) dst[r * D_] = f2bf(acc[mi][ni][r] + bias);
      }
    }
  }
}

// ---------------- flash attention (anti-causal: attend t >= s) ----------------
// Swapped QK^T (mfma(K,Q) -> S^T): lane holds 4 t-adjacent scores for one
// q-row (q=l16). P->bf16 via packed v_cvt_pk_bf16_f32 (guide-verified recipe);
// PV A-frag rebuilt IN REGISTERS via __shfl_xor + select 4x4 quad transpose
// (R1's permlane asm misrouted -> exponential blowup; shfl semantics are
// unambiguous). Ps LDS buffer deleted: no ds_write/lgkm/ds_read serial chain.
// Target A-frag (verified against R0's proven Ps read): lane(quad,l16) needs
// P[q=l16][t=quad*8+j]. Source: c0=t{quad*4+0,1}, c1=t{+2,3},
// c2=t{16+quad*4+0,1}, c3=t{16+...+2,3}. Stage1 (xor32) pairs (c0,c2),(c1,c3);
// stage2 (xor16) completes the route.
// LDS 32 KB, 4 blocks/CU. Fixed-max softmax: Q pre-scaled by K1, QK C-init K0.
__global__ __launch_bounds__(256, 4) void k_attn(
    const unsigned short* __restrict__ Qb, const unsigned short* __restrict__ Kb,
    const unsigned short* __restrict__ Vb, float* __restrict__ out) {
  __shared__ unsigned short Ks[2][2 * 64 * 32];   // [buf][dhalf][64 k][32 d]
  __shared__ unsigned short Vs[2][2 * 64 * 32];   // [buf][thalf][64 d][32 t]
  const int tid = threadIdx.x;
  const int lane = tid & 63, wave = tid >> 6;
  const int quad = lane >> 4, l16 = lane & 15;
  const int chunk = blockIdx.x >> 8;
  const int j = blockIdx.x & 255;
  int qt = j >> 3;
  if (chunk & 1) qt = 31 - qt;
  const int bh = (j & 7) + 8 * chunk;
  const int q0 = qt * 64;
  const int lrow = lane >> 2, lcol = (lane & 3) * 8;
  const int r0 = __builtin_amdgcn_readfirstlane(wave * 16);
  const f32x4 kvec = {K0_, K0_, K0_, K0_};

  s16x8 qf[2];
  {
    const unsigned short* qp = Qb + (bh * S_ + q0 + wave * 16 + l16) * D_ + quad * 8;
    qf[0] = *(const s16x8*)qp;
    qf[1] = *(const s16x8*)(qp + 32);
  }
  f32x4 o[4];
#pragma unroll
  for (int dc = 0; dc < 4; ++dc) o[dc] = (f32x4){0.f, 0.f, 0.f, 0.f};
  float l_acc = 0.f;
  const int qloc = wave * 16 + l16;  // within-tile q row this lane owns

#define DMA_KV(kt_, b_)                                                          \
  {                                                                              \
    _Pragma("unroll")                                                            \
    for (int hdc = 0; hdc < 2; ++hdc) {                                          \
      load_lds16(Kb + (bh * S_ + (kt_) * 64 + r0 + lrow) * D_ + hdc * 32 + lcol, \
                 &Ks[b_][hdc * 2048 + r0 * 32]);                                 \
      load_lds16(Vb + (bh * D_ + r0 + lrow) * S_ + (kt_) * 64 + hdc * 32 + lcol, \
                 &Vs[b_][hdc * 2048 + r0 * 32]);                                 \
    }                                                                            \
  }

  // prologue: stage tile qt into buffer 0
  DMA_KV(qt, 0);

  int buf = 0;
  for (int kt = qt; kt < S_ / 64; ++kt) {
    __syncthreads();  // Ks/Vs[buf] DMA drained; prior reads of buf^1 done
    if (kt + 1 < S_ / 64) DMA_KV(kt + 1, buf ^ 1);

    const bool diag = (kt == qt);
    const bool hi32 = (lane >= 32);
    const bool oddq = (lane & 16) != 0;
#pragma unroll
    for (int kc = 0; kc < 2; ++kc) {
      // scores^T for this 32-t half: lane reg r holds S[t=tc*16+quad*4+r][q=l16]
      unsigned c0, c1, c2, c3;
#pragma unroll
      for (int tcc = 0; tcc < 2; ++tcc) {
        const int tc = kc * 2 + tcc;
        f32x4 a = __builtin_amdgcn_mfma_f32_16x16x32_bf16(
            *(const s16x8*)&Ks[buf][(tc * 16 + l16) * 32 + quad * 8], qf[0], kvec, 0, 0, 0);
        f32x4 sc = __builtin_amdgcn_mfma_f32_16x16x32_bf16(
            *(const s16x8*)&Ks[buf][2048 + (tc * 16 + l16) * 32 + quad * 8], qf[1], a, 0, 0, 0);
        if (diag) {
          const int tb = tc * 16 + quad * 4;
#pragma unroll
          for (int r = 0; r < 4; ++r)
            if (tb + r < qloc) sc[r] = -200.f;
        }
        const float p0 = exp2f(sc[0]);
        const float p1 = exp2f(sc[1]);
        const float p2 = exp2f(sc[2]);
        const float p3 = exp2f(sc[3]);
        l_acc += (p0 + p1) + (p2 + p3);
        const unsigned lo = cvt_pk_bf16(p0, p1);  // t = quad*4+{0,1}
        const unsigned hi = cvt_pk_bf16(p2, p3);  // t = quad*4+{2,3}
        if (tcc == 0) { c0 = lo; c1 = hi; } else { c2 = lo; c3 = hi; }
      }
      // 4x4 quad transpose via shfl_xor + select -> A-frag k-order
      unsigned a0, a1, a2, a3;
      { unsigned s = __shfl_xor(c0, 32), t = __shfl_xor(c2, 32);
        a0 = hi32 ? t : c0; a2 = hi32 ? c2 : s; }
      { unsigned s = __shfl_xor(c1, 32), t = __shfl_xor(c3, 32);
        a1 = hi32 ? t : c1; a3 = hi32 ? c3 : s; }
      unsigned u0, u1, u2, u3;
      { unsigned s = __shfl_xor(a0, 16), t = __shfl_xor(a2, 16);
        u0 = oddq ? t : a0; u2 = oddq ? a2 : s; }
      { unsigned s = __shfl_xor(a1, 16), t = __shfl_xor(a3, 16);
        u1 = oddq ? t : a1; u3 = oddq ? a3 : s; }
      union { s16x8 v; unsigned u[4]; } pa;
      pa.u[0] = u0; pa.u[1] = u1; pa.u[2] = u2; pa.u[3] = u3;
#pragma unroll
      for (int dc = 0; dc < 4; ++dc) {
        s16x8 vb = *(const s16x8*)&Vs[buf][kc * 2048 + (dc * 16 + l16) * 32 + quad * 8];
        o[dc] = __builtin_amdgcn_mfma_f32_16x16x32_bf16(pa.v, vb, o[dc], 0, 0, 0);
      }
    }
    buf ^= 1;
  }
#undef DMA_KV

  // epilogue: lane's l_acc covers its quad's t-slices for q=l16; sum quads
  l_acc += __shfl_xor(l_acc, 16);
  l_acc += __shfl_xor(l_acc, 32);
  const float rinv = 1.f / l_acc;
  // o rows are q = quad*4+r; fetch that row's 1/l from the lane holding it
  float rv[4];
#pragma unroll
  for (int r = 0; r < 4; ++r) rv[r] = __shfl(rinv, quad * 4 + r);

  const int b = bh >> 4, h = bh & 15;
#pragma unroll
  for (int dc = 0; dc < 4; ++dc)
#pragma unroll
    for (int r = 0; r < 4; ++r) {
      const int s = q0 + wave * 16 + quad * 4 + r;
      out[(b * S_ + s) * (H_ * D_) + h * D_ + dc * 16 + l16] = o[dc][r] * rv[r];
    }
}

// ---------------- launch ----------------

extern "C" void kernel_launch(void* const* d_in, const int* in_sizes, int n_in,
                              void* d_out, int out_size, void* d_ws, size_t ws_size,
                              hipStream_t stream) {
  const float* x   = (const float*)d_in[0];
  const float* Wq  = (const float*)d_in[1];
  const float* bq  = (const float*)d_in[2];
  const float* Wk  = (const float*)d_in[3];
  const float* bk  = (const float*)d_in[4];
  const float* Wvd = (const float*)d_in[5];
  const float* bvd = (const float*)d_in[6];
  const float* Wvu = (const float*)d_in[7];
  const float* bvu = (const float*)d_in[8];
  float* out = (float*)d_out;

  char* ws = (char*)d_ws;
  unsigned short* xb   = (unsigned short*)(ws);                    // 8 MB
  unsigned short* Wt   = (unsigned short*)(ws + (8u << 20));       // 6 MB
  float*          ball = (float*)(ws + (14u << 20));               // 12 KB
  unsigned short* Qb   = (unsigned short*)(ws + (15u << 20));      // 8 MB
  unsigned short* Kb   = (unsigned short*)(ws + (23u << 20));      // 8 MB
  unsigned short* Vb   = (unsigned short*)(ws + (31u << 20));      // 8 MB (transposed)

  k_prep<<<8716, 256, 0, stream>>>(x, Wq, Wk, Wvd, Wvu, bq, bk, bvd, bvu, xb, Wt, ball);
  k_gemm_qkv<<<dim3(3072 / 128, 4096 / 128), 256, 0, stream>>>(xb, Wt, ball, Qb, Kb, Vb);
  k_attn<<<1024, 256, 0, stream>>>(Qb, Kb, Vb, out);
}